// Round 15
// baseline (2609.196 us; speedup 1.0000x reference)
//
#include <hip/hip_runtime.h>

typedef unsigned short u16;
typedef unsigned int   u32;
typedef __attribute__((ext_vector_type(4))) float  f32x4;
typedef __attribute__((ext_vector_type(8))) __bf16 bf16x8;
typedef __attribute__((ext_vector_type(8))) short  s16x8;
typedef __attribute__((ext_vector_type(4))) unsigned short u16x4;

#define DEVFN __device__ __forceinline__

DEVFN float bf2f(u16 u) {
    u32 v = ((u32)u) << 16;
    return __builtin_bit_cast(float, v);
}
DEVFN u16 f2bf(float f) {   // round-to-nearest-even
    u32 u = __builtin_bit_cast(u32, f);
    u32 r = u + 0x7FFFu + ((u >> 16) & 1u);
    return (u16)(r >> 16);
}

// async global->LDS, 16B per lane. LDS dest must be linear in lane order.
DEVFN void gload16(const void* g, void* l) {
    __builtin_amdgcn_global_load_lds(
        (const __attribute__((address_space(1))) void*)g,
        (__attribute__((address_space(3))) void*)l, 16, 0, 0);
}

// ---------------- fused embedding + LayerNorm (layer 0):
// x[row] = tok[idx[row]] + pos[row%T];  h[row] = bf16(LN(x[row]))
__global__ __launch_bounds__(256) void embed_ln_k(const int* __restrict__ idx,
                                                  const float* __restrict__ tok,
                                                  const float* __restrict__ pos,
                                                  const float* __restrict__ g,
                                                  const float* __restrict__ b,
                                                  float* __restrict__ x,
                                                  u16* __restrict__ out)
{
    const int row = blockIdx.x, tid = threadIdx.x;
    const int t = row & 1023;
    const int tk = idx[row];
    const float4 a = *(const float4*)&tok[(size_t)tk * 1024 + tid * 4];
    const float4 pz = *(const float4*)&pos[(size_t)t * 1024 + tid * 4];
    float4 v; v.x = a.x + pz.x; v.y = a.y + pz.y; v.z = a.z + pz.z; v.w = a.w + pz.w;
    *(float4*)&x[(size_t)row * 1024 + tid * 4] = v;
    __shared__ float red[8];
    float s = v.x + v.y + v.z + v.w;
#pragma unroll
    for (int off = 32; off > 0; off >>= 1) s += __shfl_down(s, off);
    const int lane = tid & 63, wv = tid >> 6;
    if (lane == 0) red[wv] = s;
    __syncthreads();
    const float mu = (red[0] + red[1] + red[2] + red[3]) * (1.0f / 1024.0f);
    const float dx = v.x - mu, dy = v.y - mu, dz = v.z - mu, dw = v.w - mu;
    float s2 = dx * dx + dy * dy + dz * dz + dw * dw;
#pragma unroll
    for (int off = 32; off > 0; off >>= 1) s2 += __shfl_down(s2, off);
    if (lane == 0) red[4 + wv] = s2;
    __syncthreads();
    const float var = (red[4] + red[5] + red[6] + red[7]) * (1.0f / 1024.0f);
    const float rs  = rsqrtf(var + 1e-5f);
    const float4 gv = *(const float4*)&g[tid * 4];
    const float4 bv = *(const float4*)&b[tid * 4];
    u16x4 o;
    o.x = f2bf(dx * rs * gv.x + bv.x);
    o.y = f2bf(dy * rs * gv.y + bv.y);
    o.z = f2bf(dz * rs * gv.z + bv.z);
    o.w = f2bf(dw * rs * gv.w + bv.w);
    *(u16x4*)&out[(size_t)row * 1024 + tid * 4] = o;
}

// ---------------- fp32 [K,N] -> bf16 [N,K] transpose (single matrix; head)
__global__ __launch_bounds__(256) void transpose_k(const float* __restrict__ W,
                                                   u16* __restrict__ Wt, int K, int N)
{
    __shared__ float tile[32][33];
    int n0 = blockIdx.x * 32, k0 = blockIdx.y * 32;
    int xx = threadIdx.x, ty = threadIdx.y;      // block (32,8)
#pragma unroll
    for (int yy = 0; yy < 4; ++yy) {
        int y = ty + yy * 8;
        tile[y][xx] = W[(size_t)(k0 + y) * N + n0 + xx];
    }
    __syncthreads();
#pragma unroll
    for (int yy = 0; yy < 4; ++yy) {
        int y = ty + yy * 8;
        Wt[(size_t)(n0 + y) * K + k0 + xx] = f2bf(tile[xx][y]);
    }
}

// ---------------- fused per-layer weight transpose: Wq/Wk/Wv/Wo/W1/W2 in ONE launch
__global__ __launch_bounds__(256) void transpose_all_k(
    const float* __restrict__ Wq, const float* __restrict__ Wk,
    const float* __restrict__ Wv, const float* __restrict__ Wo,
    const float* __restrict__ W1, const float* __restrict__ W2,
    u16* __restrict__ qkvT, u16* __restrict__ woT,
    u16* __restrict__ w1T, u16* __restrict__ w2T)
{
    __shared__ float tile[32][33];
    const int id = blockIdx.x;
    const float* W; u16* Wt; int K, N, bx, by;
    if (id < 3072) {
        const int m = id >> 10, t2 = id & 1023;
        W = (m == 0) ? Wq : (m == 1) ? Wk : Wv;
        Wt = qkvT + (size_t)m * 1024 * 1024;
        K = 1024; N = 1024; bx = t2 & 31; by = t2 >> 5;
    } else if (id < 4096) {
        const int t2 = id - 3072;
        W = Wo; Wt = woT; K = 1024; N = 1024; bx = t2 & 31; by = t2 >> 5;
    } else if (id < 8192) {
        const int t2 = id - 4096;
        W = W1; Wt = w1T; K = 1024; N = 4096; bx = t2 & 127; by = t2 >> 7;
    } else {
        const int t2 = id - 8192;
        W = W2; Wt = w2T; K = 4096; N = 1024; bx = t2 & 31; by = t2 >> 5;
    }
    const int n0 = bx * 32, k0 = by * 32;
    const int xx = threadIdx.x, ty = threadIdx.y;    // block (32,8)
#pragma unroll
    for (int yy = 0; yy < 4; ++yy) {
        const int y = ty + yy * 8;
        tile[y][xx] = W[(size_t)(k0 + y) * N + n0 + xx];
    }
    __syncthreads();
#pragma unroll
    for (int yy = 0; yy < 4; ++yy) {
        const int y = ty + yy * 8;
        Wt[(size_t)(n0 + y) * K + k0 + xx] = f2bf(tile[xx][y]);
    }
}

// ---------------- LayerNorm: fp32 in -> bf16 out, C=1024, one block per row
__global__ __launch_bounds__(256) void ln_k(const float* __restrict__ x,
                                            const float* __restrict__ g,
                                            const float* __restrict__ b,
                                            u16* __restrict__ out)
{
    const int row = blockIdx.x, tid = threadIdx.x;
    const float4 v = *(const float4*)&x[(size_t)row * 1024 + tid * 4];
    __shared__ float red[8];
    float s = v.x + v.y + v.z + v.w;
#pragma unroll
    for (int off = 32; off > 0; off >>= 1) s += __shfl_down(s, off);
    const int lane = tid & 63, wv = tid >> 6;
    if (lane == 0) red[wv] = s;
    __syncthreads();
    const float mu = (red[0] + red[1] + red[2] + red[3]) * (1.0f / 1024.0f);
    const float dx = v.x - mu, dy = v.y - mu, dz = v.z - mu, dw = v.w - mu;
    float s2 = dx * dx + dy * dy + dz * dz + dw * dw;
#pragma unroll
    for (int off = 32; off > 0; off >>= 1) s2 += __shfl_down(s2, off);
    if (lane == 0) red[4 + wv] = s2;
    __syncthreads();
    const float var = (red[4] + red[5] + red[6] + red[7]) * (1.0f / 1024.0f);
    const float rs  = rsqrtf(var + 1e-5f);
    const float4 gv = *(const float4*)&g[tid * 4];
    const float4 bv = *(const float4*)&b[tid * 4];
    u16x4 o;
    o.x = f2bf(dx * rs * gv.x + bv.x);
    o.y = f2bf(dy * rs * gv.y + bv.y);
    o.z = f2bf(dz * rs * gv.z + bv.z);
    o.w = f2bf(dw * rs * gv.w + bv.w);
    *(u16x4*)&out[(size_t)row * 1024 + tid * 4] = o;
}

// ---------------- bf16 MFMA GEMM (proven 128x128 dbuf; for qkv/ffn1)
template <int MODE>
__global__ __launch_bounds__(256) void gemm_bt(const u16* __restrict__ A,
                                               const u16* __restrict__ Bt,
                                               const float* __restrict__ bias,
                                               float* __restrict__ RES,
                                               u16* __restrict__ Ob,
                                               float* __restrict__ Of,
                                               int N, int K, int ntx)
{
    __shared__ __align__(16) u16 As[2][128 * 32];
    __shared__ __align__(16) u16 Bs[2][128 * 32];
    const int tid  = threadIdx.x;
    const int lane = tid & 63, wave = tid >> 6;
    const int wr = wave >> 1, wc = wave & 1;
    const int l15 = lane & 15, l4 = lane >> 4;

    const int nwg = (int)gridDim.x;
    const int bid = (int)blockIdx.x;
    const int swz = (bid & 7) * (nwg >> 3) + (bid >> 3);
    const int n0 = (swz % ntx) * 128, m0 = (swz / ntx) * 128;

    f32x4 acc[4][4];
    const f32x4 zz = {0.f, 0.f, 0.f, 0.f};
#pragma unroll
    for (int i = 0; i < 4; ++i)
#pragma unroll
        for (int j = 0; j < 4; ++j) acc[i][j] = zz;

    const int r0 = tid >> 2, q0q = (tid & 3) * 8;
    const int r1 = (tid + 256) >> 2, q1q = ((tid + 256) & 3) * 8;
    const u16* Arow0 = &A [(size_t)(m0 + r0) * K + q0q];
    const u16* Brow0 = &Bt[(size_t)(n0 + r0) * K + q0q];
    const u16* Arow1 = &A [(size_t)(m0 + r1) * K + q1q];
    const u16* Brow1 = &Bt[(size_t)(n0 + r1) * K + q1q];

    gload16(Arow0, &As[0][tid * 8]);
    gload16(Brow0, &Bs[0][tid * 8]);
    gload16(Arow1, &As[0][(tid + 256) * 8]);
    gload16(Brow1, &Bs[0][(tid + 256) * 8]);
    __syncthreads();

    const int S = K >> 5;
    int cur = 0;
    for (int s = 0; s < S; ++s) {
        if (s + 1 < S) {
            const int kn = (s + 1) << 5;
            gload16(Arow0 + kn, &As[cur ^ 1][tid * 8]);
            gload16(Brow0 + kn, &Bs[cur ^ 1][tid * 8]);
            gload16(Arow1 + kn, &As[cur ^ 1][(tid + 256) * 8]);
            gload16(Brow1 + kn, &Bs[cur ^ 1][(tid + 256) * 8]);
        }
        s16x8 af[4], bw[4];
#pragma unroll
        for (int i = 0; i < 4; ++i)
            af[i] = *(const s16x8*)&As[cur][(wr * 64 + i * 16 + l15) * 32 + l4 * 8];
#pragma unroll
        for (int j = 0; j < 4; ++j)
            bw[j] = *(const s16x8*)&Bs[cur][(wc * 64 + j * 16 + l15) * 32 + l4 * 8];
#pragma unroll
        for (int i = 0; i < 4; ++i)
#pragma unroll
            for (int j = 0; j < 4; ++j)
                acc[i][j] = __builtin_amdgcn_mfma_f32_16x16x32_bf16(
                    __builtin_bit_cast(bf16x8, af[i]),
                    __builtin_bit_cast(bf16x8, bw[j]), acc[i][j], 0, 0, 0);
        __syncthreads();
        cur ^= 1;
    }

#pragma unroll
    for (int i = 0; i < 4; ++i) {
        const int rb = m0 + wr * 64 + i * 16 + l4 * 4;
#pragma unroll
        for (int j = 0; j < 4; ++j) {
            const int col = n0 + wc * 64 + j * 16 + l15;
            const float bval = (MODE == 0) ? 0.0f : bias[col];
#pragma unroll
            for (int r = 0; r < 4; ++r) {
                const size_t o = (size_t)(rb + r) * N + col;
                const float v = acc[i][j][r];
                if (MODE == 0)      Ob[o] = f2bf(v);
                else if (MODE == 1) RES[o] += v + bval;
                else if (MODE == 2) Ob[o] = f2bf(fmaxf(v + bval, 0.0f));
                else                Of[o] = v + bval;
            }
        }
    }
}

// ---------------- 128x64-tile GEMM for N=1024/256 outputs (wo/ffn2/head)
// MODE 1: RES += acc+bias (fp32); MODE 3: Of = acc+bias (fp32 out).
template <int MODE>
__global__ __launch_bounds__(256) void gemm_n64(const u16* __restrict__ A,
                                                const u16* __restrict__ Bt,
                                                const float* __restrict__ bias,
                                                float* __restrict__ RES,
                                                float* __restrict__ Of,
                                                int N, int K, int ntx)
{
    __shared__ __align__(16) u16 As[2][128 * 32];
    __shared__ __align__(16) u16 Bs[2][64 * 32];
    const int tid  = threadIdx.x;
    const int lane = tid & 63, wave = tid >> 6;
    const int wr = wave >> 1, wc = wave & 1;       // 2x2 waves of 64x32
    const int l15 = lane & 15, l4 = lane >> 4;

    const int nwg = (int)gridDim.x;
    const int bid = (int)blockIdx.x;
    const int swz = (bid & 7) * (nwg >> 3) + (bid >> 3);
    const int n0 = (swz % ntx) * 64, m0 = (swz / ntx) * 128;

    f32x4 acc[4][2];
    const f32x4 zz = {0.f, 0.f, 0.f, 0.f};
#pragma unroll
    for (int i = 0; i < 4; ++i)
#pragma unroll
        for (int j = 0; j < 2; ++j) acc[i][j] = zz;

    const int r0 = tid >> 2, q0q = (tid & 3) * 8;
    const int r1 = (tid + 256) >> 2, q1q = ((tid + 256) & 3) * 8;
    const u16* Arow0 = &A [(size_t)(m0 + r0) * K + q0q];
    const u16* Arow1 = &A [(size_t)(m0 + r1) * K + q1q];
    const u16* Brow0 = &Bt[(size_t)(n0 + r0) * K + q0q];

    gload16(Arow0, &As[0][tid * 8]);
    gload16(Arow1, &As[0][(tid + 256) * 8]);
    gload16(Brow0, &Bs[0][tid * 8]);
    __syncthreads();

    const int S = K >> 5;
    int cur = 0;
    for (int s = 0; s < S; ++s) {
        if (s + 1 < S) {
            const int kn = (s + 1) << 5;
            gload16(Arow0 + kn, &As[cur ^ 1][tid * 8]);
            gload16(Arow1 + kn, &As[cur ^ 1][(tid + 256) * 8]);
            gload16(Brow0 + kn, &Bs[cur ^ 1][tid * 8]);
        }
        s16x8 af[4], bw[2];
#pragma unroll
        for (int i = 0; i < 4; ++i)
            af[i] = *(const s16x8*)&As[cur][(wr * 64 + i * 16 + l15) * 32 + l4 * 8];
#pragma unroll
        for (int j = 0; j < 2; ++j)
            bw[j] = *(const s16x8*)&Bs[cur][(wc * 32 + j * 16 + l15) * 32 + l4 * 8];
#pragma unroll
        for (int i = 0; i < 4; ++i)
#pragma unroll
            for (int j = 0; j < 2; ++j)
                acc[i][j] = __builtin_amdgcn_mfma_f32_16x16x32_bf16(
                    __builtin_bit_cast(bf16x8, af[i]),
                    __builtin_bit_cast(bf16x8, bw[j]), acc[i][j], 0, 0, 0);
        __syncthreads();
        cur ^= 1;
    }

#pragma unroll
    for (int i = 0; i < 4; ++i) {
        const int rb = m0 + wr * 64 + i * 16 + l4 * 4;
#pragma unroll
        for (int j = 0; j < 2; ++j) {
            const int col = n0 + wc * 32 + j * 16 + l15;
            const float bval = bias[col];
#pragma unroll
            for (int r = 0; r < 4; ++r) {
                const size_t o = (size_t)(rb + r) * N + col;
                const float v = acc[i][j][r];
                if (MODE == 1) RES[o] += v + bval;
                else           Of[o] = v + bval;
            }
        }
    }
}

// ---------------- MFMA flash attention v7b (round-12 v7 + exp2-domain softmax).
// Single-buffer LDS, async-issue-early/write-late, 2 barriers/tile, pairing
// {p, 7-p}, XCD pinning (b = id&7). Softmax in log2 domain: SCL = 0.125*log2e,
// p = exp2(S2 - m2), alpha = exp2(m2_old - m2_new), defer threshold 11.54.
__global__ __launch_bounds__(256) void attn_mfma_k(const u16* __restrict__ QKV,
                                                   u16* __restrict__ Og)
{
    const int id  = (int)(blockIdx.y * gridDim.x + blockIdx.x);
    const int b   = id & 7;                 // batch == XCD
    const int pp  = (id >> 3) & 3;          // pair index
    const int h   = id >> 5;                // 0..15
    const int tid = threadIdx.x;
    const int wq  = tid >> 6, lane = tid & 63;
    const int l15 = lane & 15, l4 = lane >> 4;

    __shared__ __align__(16) u16 Ks[64 * 64];    // K rows, chunk-XOR swizzled
    __shared__ __align__(16) u16 Vt[64][72];     // V^T rows d; u32 kv-pairs, rotated cols
    __shared__ __align__(16) u16 Ps[4][16][68];  // per-wave P
    u32* VtW = (u32*)&Vt[0][0];                  // row stride 36 u32

    const float SCL = 0.125f * 1.44269504f;      // scale * log2(e)

    const int qbase0 = pp * 128 + wq * 32;        // light q-tile rows
    const int qbase1 = (7 - pp) * 128 + wq * 32;  // heavy q-tile rows

    const u16* Qbase = QKV + (size_t)b * 1024 * 3072 + h * 64;
    const u16* Kbase = Qbase + 1024;
    const u16* Vbase = Qbase + 2048;

    s16x8 aQ[4][2];
#pragma unroll
    for (int qi = 0; qi < 4; ++qi) {
        const int qlo = ((qi >> 1) ? qbase1 : qbase0) + (qi & 1) * 16;
        const u16* qsrc = Qbase + (size_t)(qlo + l15) * 3072;
        aQ[qi][0] = *(const s16x8*)(qsrc + l4 * 8);
        aQ[qi][1] = *(const s16x8*)(qsrc + 32 + l4 * 8);
    }

    f32x4 O[4][4];
    const f32x4 zz = {0.f, 0.f, 0.f, 0.f};
    float mrow[4][4], lrow[4][4];
#pragma unroll
    for (int qi = 0; qi < 4; ++qi) {
#pragma unroll
        for (int dj = 0; dj < 4; ++dj) O[qi][dj] = zz;
#pragma unroll
        for (int r = 0; r < 4; ++r) { mrow[qi][r] = -3.0e38f; lrow[qi][r] = 0.f; }
    }

    // K reg-staging: write LDS at chunk soff^((row&7)*8) — same involution the
    // read side uses ((row&7)<<4 byte XOR).
    const int srow = tid >> 3;
    const int soff = (tid & 7) * 8;
    const int kw0  = srow * 64 + (soff ^ ((srow & 7) * 8));
    const int kw1  = (srow + 32) * 64 + (soff ^ ((srow & 7) * 8));
    const int vp  = tid >> 3;
    const int vdg = tid & 7;
    const int vc  = (vp + 4 * vdg) & 31;

    const int ntiles = 2 * (7 - pp) + 2;
    s16x8 kr0, kr1, vr0, vr1;

    // prologue: load + write tile 0
    {
        const u16* kb0 = Kbase + (size_t)srow * 3072 + soff;
        kr0 = *(const s16x8*)kb0;
        kr1 = *(const s16x8*)(kb0 + (size_t)32 * 3072);
        const u16* vb0 = Vbase + (size_t)(2 * vp) * 3072 + vdg * 8;
        vr0 = *(const s16x8*)vb0;
        vr1 = *(const s16x8*)(vb0 + 3072);
        *(s16x8*)&Ks[kw0] = kr0;
        *(s16x8*)&Ks[kw1] = kr1;
#pragma unroll
        for (int e = 0; e < 8; ++e) {
            u32 pk = (u32)(u16)vr0[e] | ((u32)(u16)vr1[e] << 16);
            VtW[(vdg * 8 + e) * 36 + vc] = pk;
        }
    }
    __syncthreads();

    for (int t = 0; t < ntiles; ++t) {
        const int kv0 = t * 64;
        const bool more = (t + 1 < ntiles);
        if (more) {   // issue next-tile loads; latency hides under compute(t)
            const u16* kb0 = Kbase + (size_t)(kv0 + 64 + srow) * 3072 + soff;
            kr0 = *(const s16x8*)kb0;
            kr1 = *(const s16x8*)(kb0 + (size_t)32 * 3072);
            const u16* vb0 = Vbase + (size_t)(kv0 + 64 + 2 * vp) * 3072 + vdg * 8;
            vr0 = *(const s16x8*)vb0;
            vr1 = *(const s16x8*)(vb0 + 3072);
        }

#pragma unroll
        for (int qi = 0; qi < 4; ++qi) {
            const int qlo = ((qi >> 1) ? qbase1 : qbase0) + (qi & 1) * 16;
            if (kv0 > qlo + 15) continue;            // fully masked frag
            f32x4 S[4];
            __builtin_amdgcn_s_setprio(1);
#pragma unroll
            for (int kc = 0; kc < 4; ++kc) {
                const int row = kc * 16 + l15;
                const int sw = (row & 7) << 4;
                const char* Kb = (const char*)Ks;
                f32x4 s = zz;
                s16x8 bK0 = *(const s16x8*)(Kb + ((row * 128 + l4 * 16) ^ sw));
                s16x8 bK1 = *(const s16x8*)(Kb + ((row * 128 + 64 + l4 * 16) ^ sw));
                s = __builtin_amdgcn_mfma_f32_16x16x32_bf16(
                    __builtin_bit_cast(bf16x8, aQ[qi][0]), __builtin_bit_cast(bf16x8, bK0), s, 0, 0, 0);
                s = __builtin_amdgcn_mfma_f32_16x16x32_bf16(
                    __builtin_bit_cast(bf16x8, aQ[qi][1]), __builtin_bit_cast(bf16x8, bK1), s, 0, 0, 0);
#pragma unroll
                for (int r = 0; r < 4; ++r) S[kc][r] = s[r] * SCL;   // log2 domain
            }
            __builtin_amdgcn_s_setprio(0);
            if (kv0 + 63 > qlo) {
#pragma unroll
                for (int kc = 0; kc < 4; ++kc) {
                    const int k = kv0 + kc * 16 + l15;
#pragma unroll
                    for (int r = 0; r < 4; ++r)
                        if (k > qlo + l4 * 4 + r) S[kc][r] = -3.0e38f;
                }
            }
            float mloc[4];
#pragma unroll
            for (int r = 0; r < 4; ++r)
                mloc[r] = fmaxf(fmaxf(S[0][r], S[1][r]), fmaxf(S[2][r], S[3][r]));
#pragma unroll
            for (int off = 1; off < 16; off <<= 1)
#pragma unroll
                for (int r = 0; r < 4; ++r) mloc[r] = fmaxf(mloc[r], __shfl_xor(mloc[r], off));
            // defer-max (T13): 8 ln-units = 11.54 log2-units; P bounded by 2^11.54
            bool stable = (mloc[0] <= mrow[qi][0] + 11.54f) && (mloc[1] <= mrow[qi][1] + 11.54f)
                       && (mloc[2] <= mrow[qi][2] + 11.54f) && (mloc[3] <= mrow[qi][3] + 11.54f);
            if (!__all(stable)) {
#pragma unroll
                for (int r = 0; r < 4; ++r) {
                    const float mnew = fmaxf(mrow[qi][r], mloc[r]);
                    const float al = exp2f(mrow[qi][r] - mnew);
                    mrow[qi][r] = mnew;
                    lrow[qi][r] *= al;
#pragma unroll
                    for (int dj = 0; dj < 4; ++dj) O[qi][dj][r] *= al;
                }
            }
#pragma unroll
            for (int kc = 0; kc < 4; ++kc)
#pragma unroll
                for (int r = 0; r < 4; ++r) {
                    const float p = exp2f(S[kc][r] - mrow[qi][r]);
                    Ps[wq][l4 * 4 + r][kc * 16 + l15] = f2bf(p);
                    lrow[qi][r] += p;
                }
            __builtin_amdgcn_s_setprio(1);
#pragma unroll
            for (int kk = 0; kk < 2; ++kk) {
                s16x8 aP = *(const s16x8*)&Ps[wq][l15][kk * 32 + l4 * 8];
#pragma unroll
                for (int dj = 0; dj < 4; ++dj) {
                    const int d = dj * 16 + l15;
                    const int c = (kk * 16 + l4 * 4 + 4 * ((d >> 3) & 7)) & 31;
                    s16x8 bV = *(const s16x8*)&VtW[d * 36 + c];
                    O[qi][dj] = __builtin_amdgcn_mfma_f32_16x16x32_bf16(
                        __builtin_bit_cast(bf16x8, aP), __builtin_bit_cast(bf16x8, bV),
                        O[qi][dj], 0, 0, 0);
                }
            }
            __builtin_amdgcn_s_setprio(0);
        }

        __syncthreads();   // all waves done reading Ks/Vt of tile t
        if (more) {        // write-late: staged regs -> LDS
            *(s16x8*)&Ks[kw0] = kr0;
            *(s16x8*)&Ks[kw1] = kr1;
#pragma unroll
            for (int e = 0; e < 8; ++e) {
                u32 pk = (u32)(u16)vr0[e] | ((u32)(u16)vr1[e] << 16);
                VtW[(vdg * 8 + e) * 36 + vc] = pk;
            }
        }
        __syncthreads();   // staging visible
    }
    // epilogue: reduce partial l, then O/l for both q-tiles
#pragma unroll
    for (int qi = 0; qi < 4; ++qi)
#pragma unroll
        for (int r = 0; r < 4; ++r) {
            float s = lrow[qi][r];
#pragma unroll
            for (int off = 1; off < 16; off <<= 1) s += __shfl_xor(s, off);
            lrow[qi][r] = s;
        }
#pragma unroll
    for (int qi = 0; qi < 4; ++qi) {
        const int qlo = ((qi >> 1) ? qbase1 : qbase0) + (qi & 1) * 16;
#pragma unroll
        for (int dj = 0; dj < 4; ++dj)
#pragma unroll
            for (int r = 0; r < 4; ++r) {
                const size_t o = ((size_t)(b * 1024 + qlo + l4 * 4 + r)) * 1024
                               + h * 64 + dj * 16 + l15;
                Og[o] = f2bf(O[qi][dj][r] / lrow[qi][r]);
            }
    }
}

// ---------------- orchestration
extern "C" void kernel_launch(void* const* d_in, const int* in_sizes, int n_in,
                              void* d_out, int out_size, void* d_ws, size_t ws_size,
                              hipStream_t stream)
{
    (void)in_sizes; (void)n_in; (void)out_size; (void)ws_size;
    const int*   idx  = (const int*)  d_in[0];
    const float* tok  = (const float*)d_in[1];
    const float* pos  = (const float*)d_in[2];
    const float* Wq   = (const float*)d_in[3];
    const float* Wk   = (const float*)d_in[4];
    const float* Wv   = (const float*)d_in[5];
    const float* Wo   = (const float*)d_in[6];
    const float* bo   = (const float*)d_in[7];
    const float* ln1g = (const float*)d_in[8];
    const float* ln1b = (const float*)d_in[9];
    const float* ln2g = (const float*)d_in[10];
    const float* ln2b = (const float*)d_in[11];
    const float* W1   = (const float*)d_in[12];
    const float* b1   = (const float*)d_in[13];
    const float* W2   = (const float*)d_in[14];
    const float* b2   = (const float*)d_in[15];
    const float* lnfg = (const float*)d_in[16];
    const float* lnfb = (const float*)d_in[17];
    const float* Wh   = (const float*)d_in[18];
    const float* bh   = (const float*)d_in[19];

    char* p = (char*)d_ws;
    float* x  = (float*)p; p += (size_t)8192 * 1024 * 4;
    u16* h    = (u16*)p;   p += (size_t)8192 * 1024 * 2;
    u16* qkv  = (u16*)p;   p += (size_t)8192 * 3072 * 2;
    u16* ab   = (u16*)p;   p += (size_t)8192 * 1024 * 2;
    u16* fb   = (u16*)p;   p += (size_t)8192 * 4096 * 2;
    u16* wqT  = (u16*)p;   p += (size_t)1024 * 1024 * 2;   // wq/wk/wv contiguous -> [3072][1024]
    u16* wkT  = (u16*)p;   p += (size_t)1024 * 1024 * 2;
    u16* wvT  = (u16*)p;   p += (size_t)1024 * 1024 * 2;
    u16* woT  = (u16*)p;   p += (size_t)1024 * 1024 * 2;
    u16* w1T  = (u16*)p;   p += (size_t)1024 * 4096 * 2;
    u16* w2T  = (u16*)p;   p += (size_t)4096 * 1024 * 2;
    u16* whT  = (u16*)p;   p += (size_t)1024 * 256 * 2;
    (void)wkT; (void)wvT;

    const dim3 tb(32, 8);
    for (int l = 0; l < 6; ++l) {
        transpose_all_k<<<12288, tb, 0, stream>>>(
            Wq + (size_t)l * 1048576, Wk + (size_t)l * 1048576,
            Wv + (size_t)l * 1048576, Wo + (size_t)l * 1048576,
            W1 + (size_t)l * 4194304, W2 + (size_t)l * 4194304,
            wqT, woT, w1T, w2T);

        if (l == 0)
            embed_ln_k<<<8192, 256, 0, stream>>>(idx, tok, pos, ln1g, ln1b, x, h);
        else
            ln_k<<<8192, 256, 0, stream>>>(x, ln1g + l * 1024, ln1b + l * 1024, h);
        gemm_bt<0><<<1536, 256, 0, stream>>>(h, wqT, nullptr, nullptr, qkv, nullptr, 3072, 1024, 24);
        attn_mfma_k<<<dim3(4, 128), 256, 0, stream>>>(qkv, ab);
        gemm_n64<1><<<1024, 256, 0, stream>>>(ab, woT, bo + l * 1024, x, nullptr, 1024, 1024, 16);
        ln_k<<<8192, 256, 0, stream>>>(x, ln2g + l * 1024, ln2b + l * 1024, h);
        gemm_bt<2><<<2048, 256, 0, stream>>>(h, w1T, b1 + l * 4096, nullptr, fb, nullptr, 4096, 1024, 32);
        gemm_n64<1><<<1024, 256, 0, stream>>>(fb, w2T, b2 + l * 1024, x, nullptr, 1024, 4096, 16);
    }
    transpose_k<<<dim3(8, 32), tb, 0, stream>>>(Wh, whT, 1024, 256);
    ln_k<<<8192, 256, 0, stream>>>(x, lnfg, lnfb, h);
    gemm_n64<3><<<256, 256, 0, stream>>>(h, whT, bh, nullptr, (float*)d_out, 256, 1024, 4);
}

// Round 16
// 2545.355 us; speedup vs baseline: 1.0251x; 1.0251x over previous
//
#include <hip/hip_runtime.h>

typedef unsigned short u16;
typedef unsigned int   u32;
typedef __attribute__((ext_vector_type(4))) float  f32x4;
typedef __attribute__((ext_vector_type(8))) __bf16 bf16x8;
typedef __attribute__((ext_vector_type(8))) short  s16x8;
typedef __attribute__((ext_vector_type(4))) unsigned short u16x4;

#define DEVFN __device__ __forceinline__

DEVFN float bf2f(u16 u) {
    u32 v = ((u32)u) << 16;
    return __builtin_bit_cast(float, v);
}
DEVFN u16 f2bf(float f) {   // round-to-nearest-even
    u32 u = __builtin_bit_cast(u32, f);
    u32 r = u + 0x7FFFu + ((u >> 16) & 1u);
    return (u16)(r >> 16);
}

// async global->LDS, 16B per lane. LDS dest must be linear in lane order.
DEVFN void gload16(const void* g, void* l) {
    __builtin_amdgcn_global_load_lds(
        (const __attribute__((address_space(1))) void*)g,
        (__attribute__((address_space(3))) void*)l, 16, 0, 0);
}

// ---------------- fused embedding + LayerNorm (layer 0):
// x[row] = tok[idx[row]] + pos[row%T];  h[row] = bf16(LN(x[row]))
__global__ __launch_bounds__(256) void embed_ln_k(const int* __restrict__ idx,
                                                  const float* __restrict__ tok,
                                                  const float* __restrict__ pos,
                                                  const float* __restrict__ g,
                                                  const float* __restrict__ b,
                                                  float* __restrict__ x,
                                                  u16* __restrict__ out)
{
    const int row = blockIdx.x, tid = threadIdx.x;
    const int t = row & 1023;
    const int tk = idx[row];
    const float4 a = *(const float4*)&tok[(size_t)tk * 1024 + tid * 4];
    const float4 pz = *(const float4*)&pos[(size_t)t * 1024 + tid * 4];
    float4 v; v.x = a.x + pz.x; v.y = a.y + pz.y; v.z = a.z + pz.z; v.w = a.w + pz.w;
    *(float4*)&x[(size_t)row * 1024 + tid * 4] = v;
    __shared__ float red[8];
    float s = v.x + v.y + v.z + v.w;
#pragma unroll
    for (int off = 32; off > 0; off >>= 1) s += __shfl_down(s, off);
    const int lane = tid & 63, wv = tid >> 6;
    if (lane == 0) red[wv] = s;
    __syncthreads();
    const float mu = (red[0] + red[1] + red[2] + red[3]) * (1.0f / 1024.0f);
    const float dx = v.x - mu, dy = v.y - mu, dz = v.z - mu, dw = v.w - mu;
    float s2 = dx * dx + dy * dy + dz * dz + dw * dw;
#pragma unroll
    for (int off = 32; off > 0; off >>= 1) s2 += __shfl_down(s2, off);
    if (lane == 0) red[4 + wv] = s2;
    __syncthreads();
    const float var = (red[4] + red[5] + red[6] + red[7]) * (1.0f / 1024.0f);
    const float rs  = rsqrtf(var + 1e-5f);
    const float4 gv = *(const float4*)&g[tid * 4];
    const float4 bv = *(const float4*)&b[tid * 4];
    u16x4 o;
    o.x = f2bf(dx * rs * gv.x + bv.x);
    o.y = f2bf(dy * rs * gv.y + bv.y);
    o.z = f2bf(dz * rs * gv.z + bv.z);
    o.w = f2bf(dw * rs * gv.w + bv.w);
    *(u16x4*)&out[(size_t)row * 1024 + tid * 4] = o;
}

// ---------------- fp32 [K,N] -> bf16 [N,K] transpose (single matrix; head)
__global__ __launch_bounds__(256) void transpose_k(const float* __restrict__ W,
                                                   u16* __restrict__ Wt, int K, int N)
{
    __shared__ float tile[32][33];
    int n0 = blockIdx.x * 32, k0 = blockIdx.y * 32;
    int xx = threadIdx.x, ty = threadIdx.y;      // block (32,8)
#pragma unroll
    for (int yy = 0; yy < 4; ++yy) {
        int y = ty + yy * 8;
        tile[y][xx] = W[(size_t)(k0 + y) * N + n0 + xx];
    }
    __syncthreads();
#pragma unroll
    for (int yy = 0; yy < 4; ++yy) {
        int y = ty + yy * 8;
        Wt[(size_t)(n0 + y) * K + k0 + xx] = f2bf(tile[xx][y]);
    }
}

// ---------------- fused per-layer weight transpose: Wq/Wk/Wv/Wo/W1/W2 in ONE launch
__global__ __launch_bounds__(256) void transpose_all_k(
    const float* __restrict__ Wq, const float* __restrict__ Wk,
    const float* __restrict__ Wv, const float* __restrict__ Wo,
    const float* __restrict__ W1, const float* __restrict__ W2,
    u16* __restrict__ qkvT, u16* __restrict__ woT,
    u16* __restrict__ w1T, u16* __restrict__ w2T)
{
    __shared__ float tile[32][33];
    const int id = blockIdx.x;
    const float* W; u16* Wt; int K, N, bx, by;
    if (id < 3072) {
        const int m = id >> 10, t2 = id & 1023;
        W = (m == 0) ? Wq : (m == 1) ? Wk : Wv;
        Wt = qkvT + (size_t)m * 1024 * 1024;
        K = 1024; N = 1024; bx = t2 & 31; by = t2 >> 5;
    } else if (id < 4096) {
        const int t2 = id - 3072;
        W = Wo; Wt = woT; K = 1024; N = 1024; bx = t2 & 31; by = t2 >> 5;
    } else if (id < 8192) {
        const int t2 = id - 4096;
        W = W1; Wt = w1T; K = 1024; N = 4096; bx = t2 & 127; by = t2 >> 7;
    } else {
        const int t2 = id - 8192;
        W = W2; Wt = w2T; K = 4096; N = 1024; bx = t2 & 31; by = t2 >> 5;
    }
    const int n0 = bx * 32, k0 = by * 32;
    const int xx = threadIdx.x, ty = threadIdx.y;    // block (32,8)
#pragma unroll
    for (int yy = 0; yy < 4; ++yy) {
        const int y = ty + yy * 8;
        tile[y][xx] = W[(size_t)(k0 + y) * N + n0 + xx];
    }
    __syncthreads();
#pragma unroll
    for (int yy = 0; yy < 4; ++yy) {
        const int y = ty + yy * 8;
        Wt[(size_t)(n0 + y) * K + k0 + xx] = f2bf(tile[xx][y]);
    }
}

// ---------------- LayerNorm: fp32 in -> bf16 out, C=1024, one block per row
__global__ __launch_bounds__(256) void ln_k(const float* __restrict__ x,
                                            const float* __restrict__ g,
                                            const float* __restrict__ b,
                                            u16* __restrict__ out)
{
    const int row = blockIdx.x, tid = threadIdx.x;
    const float4 v = *(const float4*)&x[(size_t)row * 1024 + tid * 4];
    __shared__ float red[8];
    float s = v.x + v.y + v.z + v.w;
#pragma unroll
    for (int off = 32; off > 0; off >>= 1) s += __shfl_down(s, off);
    const int lane = tid & 63, wv = tid >> 6;
    if (lane == 0) red[wv] = s;
    __syncthreads();
    const float mu = (red[0] + red[1] + red[2] + red[3]) * (1.0f / 1024.0f);
    const float dx = v.x - mu, dy = v.y - mu, dz = v.z - mu, dw = v.w - mu;
    float s2 = dx * dx + dy * dy + dz * dz + dw * dw;
#pragma unroll
    for (int off = 32; off > 0; off >>= 1) s2 += __shfl_down(s2, off);
    if (lane == 0) red[4 + wv] = s2;
    __syncthreads();
    const float var = (red[4] + red[5] + red[6] + red[7]) * (1.0f / 1024.0f);
    const float rs  = rsqrtf(var + 1e-5f);
    const float4 gv = *(const float4*)&g[tid * 4];
    const float4 bv = *(const float4*)&b[tid * 4];
    u16x4 o;
    o.x = f2bf(dx * rs * gv.x + bv.x);
    o.y = f2bf(dy * rs * gv.y + bv.y);
    o.z = f2bf(dz * rs * gv.z + bv.z);
    o.w = f2bf(dw * rs * gv.w + bv.w);
    *(u16x4*)&out[(size_t)row * 1024 + tid * 4] = o;
}

// ---------------- bf16 MFMA GEMM (proven 128x128 dbuf; for qkv/ffn1)
template <int MODE>
__global__ __launch_bounds__(256) void gemm_bt(const u16* __restrict__ A,
                                               const u16* __restrict__ Bt,
                                               const float* __restrict__ bias,
                                               float* __restrict__ RES,
                                               u16* __restrict__ Ob,
                                               float* __restrict__ Of,
                                               int N, int K, int ntx)
{
    __shared__ __align__(16) u16 As[2][128 * 32];
    __shared__ __align__(16) u16 Bs[2][128 * 32];
    const int tid  = threadIdx.x;
    const int lane = tid & 63, wave = tid >> 6;
    const int wr = wave >> 1, wc = wave & 1;
    const int l15 = lane & 15, l4 = lane >> 4;

    const int nwg = (int)gridDim.x;
    const int bid = (int)blockIdx.x;
    const int swz = (bid & 7) * (nwg >> 3) + (bid >> 3);
    const int n0 = (swz % ntx) * 128, m0 = (swz / ntx) * 128;

    f32x4 acc[4][4];
    const f32x4 zz = {0.f, 0.f, 0.f, 0.f};
#pragma unroll
    for (int i = 0; i < 4; ++i)
#pragma unroll
        for (int j = 0; j < 4; ++j) acc[i][j] = zz;

    const int r0 = tid >> 2, q0q = (tid & 3) * 8;
    const int r1 = (tid + 256) >> 2, q1q = ((tid + 256) & 3) * 8;
    const u16* Arow0 = &A [(size_t)(m0 + r0) * K + q0q];
    const u16* Brow0 = &Bt[(size_t)(n0 + r0) * K + q0q];
    const u16* Arow1 = &A [(size_t)(m0 + r1) * K + q1q];
    const u16* Brow1 = &Bt[(size_t)(n0 + r1) * K + q1q];

    gload16(Arow0, &As[0][tid * 8]);
    gload16(Brow0, &Bs[0][tid * 8]);
    gload16(Arow1, &As[0][(tid + 256) * 8]);
    gload16(Brow1, &Bs[0][(tid + 256) * 8]);
    __syncthreads();

    const int S = K >> 5;
    int cur = 0;
    for (int s = 0; s < S; ++s) {
        if (s + 1 < S) {
            const int kn = (s + 1) << 5;
            gload16(Arow0 + kn, &As[cur ^ 1][tid * 8]);
            gload16(Brow0 + kn, &Bs[cur ^ 1][tid * 8]);
            gload16(Arow1 + kn, &As[cur ^ 1][(tid + 256) * 8]);
            gload16(Brow1 + kn, &Bs[cur ^ 1][(tid + 256) * 8]);
        }
        s16x8 af[4], bw[4];
#pragma unroll
        for (int i = 0; i < 4; ++i)
            af[i] = *(const s16x8*)&As[cur][(wr * 64 + i * 16 + l15) * 32 + l4 * 8];
#pragma unroll
        for (int j = 0; j < 4; ++j)
            bw[j] = *(const s16x8*)&Bs[cur][(wc * 64 + j * 16 + l15) * 32 + l4 * 8];
#pragma unroll
        for (int i = 0; i < 4; ++i)
#pragma unroll
            for (int j = 0; j < 4; ++j)
                acc[i][j] = __builtin_amdgcn_mfma_f32_16x16x32_bf16(
                    __builtin_bit_cast(bf16x8, af[i]),
                    __builtin_bit_cast(bf16x8, bw[j]), acc[i][j], 0, 0, 0);
        __syncthreads();
        cur ^= 1;
    }

#pragma unroll
    for (int i = 0; i < 4; ++i) {
        const int rb = m0 + wr * 64 + i * 16 + l4 * 4;
#pragma unroll
        for (int j = 0; j < 4; ++j) {
            const int col = n0 + wc * 64 + j * 16 + l15;
            const float bval = (MODE == 0) ? 0.0f : bias[col];
#pragma unroll
            for (int r = 0; r < 4; ++r) {
                const size_t o = (size_t)(rb + r) * N + col;
                const float v = acc[i][j][r];
                if (MODE == 0)      Ob[o] = f2bf(v);
                else if (MODE == 1) RES[o] += v + bval;
                else if (MODE == 2) Ob[o] = f2bf(fmaxf(v + bval, 0.0f));
                else                Of[o] = v + bval;
            }
        }
    }
}

// ---------------- 128x64-tile GEMM for N=1024/256 outputs (wo/ffn2/head)
// MODE 1: RES += acc+bias (fp32); MODE 3: Of = acc+bias (fp32 out).
template <int MODE>
__global__ __launch_bounds__(256) void gemm_n64(const u16* __restrict__ A,
                                                const u16* __restrict__ Bt,
                                                const float* __restrict__ bias,
                                                float* __restrict__ RES,
                                                float* __restrict__ Of,
                                                int N, int K, int ntx)
{
    __shared__ __align__(16) u16 As[2][128 * 32];
    __shared__ __align__(16) u16 Bs[2][64 * 32];
    const int tid  = threadIdx.x;
    const int lane = tid & 63, wave = tid >> 6;
    const int wr = wave >> 1, wc = wave & 1;       // 2x2 waves of 64x32
    const int l15 = lane & 15, l4 = lane >> 4;

    const int nwg = (int)gridDim.x;
    const int bid = (int)blockIdx.x;
    const int swz = (bid & 7) * (nwg >> 3) + (bid >> 3);
    const int n0 = (swz % ntx) * 64, m0 = (swz / ntx) * 128;

    f32x4 acc[4][2];
    const f32x4 zz = {0.f, 0.f, 0.f, 0.f};
#pragma unroll
    for (int i = 0; i < 4; ++i)
#pragma unroll
        for (int j = 0; j < 2; ++j) acc[i][j] = zz;

    const int r0 = tid >> 2, q0q = (tid & 3) * 8;
    const int r1 = (tid + 256) >> 2, q1q = ((tid + 256) & 3) * 8;
    const u16* Arow0 = &A [(size_t)(m0 + r0) * K + q0q];
    const u16* Arow1 = &A [(size_t)(m0 + r1) * K + q1q];
    const u16* Brow0 = &Bt[(size_t)(n0 + r0) * K + q0q];

    gload16(Arow0, &As[0][tid * 8]);
    gload16(Arow1, &As[0][(tid + 256) * 8]);
    gload16(Brow0, &Bs[0][tid * 8]);
    __syncthreads();

    const int S = K >> 5;
    int cur = 0;
    for (int s = 0; s < S; ++s) {
        if (s + 1 < S) {
            const int kn = (s + 1) << 5;
            gload16(Arow0 + kn, &As[cur ^ 1][tid * 8]);
            gload16(Arow1 + kn, &As[cur ^ 1][(tid + 256) * 8]);
            gload16(Brow0 + kn, &Bs[cur ^ 1][tid * 8]);
        }
        s16x8 af[4], bw[2];
#pragma unroll
        for (int i = 0; i < 4; ++i)
            af[i] = *(const s16x8*)&As[cur][(wr * 64 + i * 16 + l15) * 32 + l4 * 8];
#pragma unroll
        for (int j = 0; j < 2; ++j)
            bw[j] = *(const s16x8*)&Bs[cur][(wc * 32 + j * 16 + l15) * 32 + l4 * 8];
#pragma unroll
        for (int i = 0; i < 4; ++i)
#pragma unroll
            for (int j = 0; j < 2; ++j)
                acc[i][j] = __builtin_amdgcn_mfma_f32_16x16x32_bf16(
                    __builtin_bit_cast(bf16x8, af[i]),
                    __builtin_bit_cast(bf16x8, bw[j]), acc[i][j], 0, 0, 0);
        __syncthreads();
        cur ^= 1;
    }

#pragma unroll
    for (int i = 0; i < 4; ++i) {
        const int rb = m0 + wr * 64 + i * 16 + l4 * 4;
#pragma unroll
        for (int j = 0; j < 2; ++j) {
            const int col = n0 + wc * 32 + j * 16 + l15;
            const float bval = bias[col];
#pragma unroll
            for (int r = 0; r < 4; ++r) {
                const size_t o = (size_t)(rb + r) * N + col;
                const float v = acc[i][j][r];
                if (MODE == 1) RES[o] += v + bval;
                else           Of[o] = v + bval;
            }
        }
    }
}

// ---------------- MFMA flash attention v7 (round-12 proven: __expf, THR=8).
// Single-buffer LDS, async-issue-early/write-late, 2 barriers/tile, pairing
// {p, 7-p}, XCD pinning (b = id&7).
__global__ __launch_bounds__(256) void attn_mfma_k(const u16* __restrict__ QKV,
                                                   u16* __restrict__ Og)
{
    const int id  = (int)(blockIdx.y * gridDim.x + blockIdx.x);
    const int b   = id & 7;                 // batch == XCD
    const int pp  = (id >> 3) & 3;          // pair index
    const int h   = id >> 5;                // 0..15
    const int tid = threadIdx.x;
    const int wq  = tid >> 6, lane = tid & 63;
    const int l15 = lane & 15, l4 = lane >> 4;

    __shared__ __align__(16) u16 Ks[64 * 64];    // K rows, chunk-XOR swizzled
    __shared__ __align__(16) u16 Vt[64][72];     // V^T rows d; u32 kv-pairs, rotated cols
    __shared__ __align__(16) u16 Ps[4][16][68];  // per-wave P
    u32* VtW = (u32*)&Vt[0][0];                  // row stride 36 u32

    const int qbase0 = pp * 128 + wq * 32;        // light q-tile rows
    const int qbase1 = (7 - pp) * 128 + wq * 32;  // heavy q-tile rows

    const u16* Qbase = QKV + (size_t)b * 1024 * 3072 + h * 64;
    const u16* Kbase = Qbase + 1024;
    const u16* Vbase = Qbase + 2048;

    s16x8 aQ[4][2];
#pragma unroll
    for (int qi = 0; qi < 4; ++qi) {
        const int qlo = ((qi >> 1) ? qbase1 : qbase0) + (qi & 1) * 16;
        const u16* qsrc = Qbase + (size_t)(qlo + l15) * 3072;
        aQ[qi][0] = *(const s16x8*)(qsrc + l4 * 8);
        aQ[qi][1] = *(const s16x8*)(qsrc + 32 + l4 * 8);
    }

    f32x4 O[4][4];
    const f32x4 zz = {0.f, 0.f, 0.f, 0.f};
    float mrow[4][4], lrow[4][4];
#pragma unroll
    for (int qi = 0; qi < 4; ++qi) {
#pragma unroll
        for (int dj = 0; dj < 4; ++dj) O[qi][dj] = zz;
#pragma unroll
        for (int r = 0; r < 4; ++r) { mrow[qi][r] = -3.0e38f; lrow[qi][r] = 0.f; }
    }

    // K reg-staging: write LDS at chunk soff^((row&7)*8) — same involution the
    // read side uses ((row&7)<<4 byte XOR).
    const int srow = tid >> 3;
    const int soff = (tid & 7) * 8;
    const int kw0  = srow * 64 + (soff ^ ((srow & 7) * 8));
    const int kw1  = (srow + 32) * 64 + (soff ^ ((srow & 7) * 8));
    const int vp  = tid >> 3;
    const int vdg = tid & 7;
    const int vc  = (vp + 4 * vdg) & 31;

    const int ntiles = 2 * (7 - pp) + 2;
    s16x8 kr0, kr1, vr0, vr1;

    // prologue: load + write tile 0
    {
        const u16* kb0 = Kbase + (size_t)srow * 3072 + soff;
        kr0 = *(const s16x8*)kb0;
        kr1 = *(const s16x8*)(kb0 + (size_t)32 * 3072);
        const u16* vb0 = Vbase + (size_t)(2 * vp) * 3072 + vdg * 8;
        vr0 = *(const s16x8*)vb0;
        vr1 = *(const s16x8*)(vb0 + 3072);
        *(s16x8*)&Ks[kw0] = kr0;
        *(s16x8*)&Ks[kw1] = kr1;
#pragma unroll
        for (int e = 0; e < 8; ++e) {
            u32 pk = (u32)(u16)vr0[e] | ((u32)(u16)vr1[e] << 16);
            VtW[(vdg * 8 + e) * 36 + vc] = pk;
        }
    }
    __syncthreads();

    for (int t = 0; t < ntiles; ++t) {
        const int kv0 = t * 64;
        const bool more = (t + 1 < ntiles);
        if (more) {   // issue next-tile loads; latency hides under compute(t)
            const u16* kb0 = Kbase + (size_t)(kv0 + 64 + srow) * 3072 + soff;
            kr0 = *(const s16x8*)kb0;
            kr1 = *(const s16x8*)(kb0 + (size_t)32 * 3072);
            const u16* vb0 = Vbase + (size_t)(kv0 + 64 + 2 * vp) * 3072 + vdg * 8;
            vr0 = *(const s16x8*)vb0;
            vr1 = *(const s16x8*)(vb0 + 3072);
        }

#pragma unroll
        for (int qi = 0; qi < 4; ++qi) {
            const int qlo = ((qi >> 1) ? qbase1 : qbase0) + (qi & 1) * 16;
            if (kv0 > qlo + 15) continue;            // fully masked frag
            f32x4 S[4];
            __builtin_amdgcn_s_setprio(1);
#pragma unroll
            for (int kc = 0; kc < 4; ++kc) {
                const int row = kc * 16 + l15;
                const int sw = (row & 7) << 4;
                const char* Kb = (const char*)Ks;
                f32x4 s = zz;
                s16x8 bK0 = *(const s16x8*)(Kb + ((row * 128 + l4 * 16) ^ sw));
                s16x8 bK1 = *(const s16x8*)(Kb + ((row * 128 + 64 + l4 * 16) ^ sw));
                s = __builtin_amdgcn_mfma_f32_16x16x32_bf16(
                    __builtin_bit_cast(bf16x8, aQ[qi][0]), __builtin_bit_cast(bf16x8, bK0), s, 0, 0, 0);
                s = __builtin_amdgcn_mfma_f32_16x16x32_bf16(
                    __builtin_bit_cast(bf16x8, aQ[qi][1]), __builtin_bit_cast(bf16x8, bK1), s, 0, 0, 0);
#pragma unroll
                for (int r = 0; r < 4; ++r) S[kc][r] = s[r] * 0.125f;
            }
            __builtin_amdgcn_s_setprio(0);
            if (kv0 + 63 > qlo) {
#pragma unroll
                for (int kc = 0; kc < 4; ++kc) {
                    const int k = kv0 + kc * 16 + l15;
#pragma unroll
                    for (int r = 0; r < 4; ++r)
                        if (k > qlo + l4 * 4 + r) S[kc][r] = -3.0e38f;
                }
            }
            float mloc[4];
#pragma unroll
            for (int r = 0; r < 4; ++r)
                mloc[r] = fmaxf(fmaxf(S[0][r], S[1][r]), fmaxf(S[2][r], S[3][r]));
#pragma unroll
            for (int off = 1; off < 16; off <<= 1)
#pragma unroll
                for (int r = 0; r < 4; ++r) mloc[r] = fmaxf(mloc[r], __shfl_xor(mloc[r], off));
            bool stable = (mloc[0] <= mrow[qi][0] + 8.f) && (mloc[1] <= mrow[qi][1] + 8.f)
                       && (mloc[2] <= mrow[qi][2] + 8.f) && (mloc[3] <= mrow[qi][3] + 8.f);
            if (!__all(stable)) {
#pragma unroll
                for (int r = 0; r < 4; ++r) {
                    const float mnew = fmaxf(mrow[qi][r], mloc[r]);
                    const float al = __expf(mrow[qi][r] - mnew);
                    mrow[qi][r] = mnew;
                    lrow[qi][r] *= al;
#pragma unroll
                    for (int dj = 0; dj < 4; ++dj) O[qi][dj][r] *= al;
                }
            }
#pragma unroll
            for (int kc = 0; kc < 4; ++kc)
#pragma unroll
                for (int r = 0; r < 4; ++r) {
                    const float p = __expf(S[kc][r] - mrow[qi][r]);
                    Ps[wq][l4 * 4 + r][kc * 16 + l15] = f2bf(p);
                    lrow[qi][r] += p;
                }
            __builtin_amdgcn_s_setprio(1);
#pragma unroll
            for (int kk = 0; kk < 2; ++kk) {
                s16x8 aP = *(const s16x8*)&Ps[wq][l15][kk * 32 + l4 * 8];
#pragma unroll
                for (int dj = 0; dj < 4; ++dj) {
                    const int d = dj * 16 + l15;
                    const int c = (kk * 16 + l4 * 4 + 4 * ((d >> 3) & 7)) & 31;
                    s16x8 bV = *(const s16x8*)&VtW[d * 36 + c];
                    O[qi][dj] = __builtin_amdgcn_mfma_f32_16x16x32_bf16(
                        __builtin_bit_cast(bf16x8, aP), __builtin_bit_cast(bf16x8, bV),
                        O[qi][dj], 0, 0, 0);
                }
            }
            __builtin_amdgcn_s_setprio(0);
        }

        __syncthreads();   // all waves done reading Ks/Vt of tile t
        if (more) {        // write-late: staged regs -> LDS
            *(s16x8*)&Ks[kw0] = kr0;
            *(s16x8*)&Ks[kw1] = kr1;
#pragma unroll
            for (int e = 0; e < 8; ++e) {
                u32 pk = (u32)(u16)vr0[e] | ((u32)(u16)vr1[e] << 16);
                VtW[(vdg * 8 + e) * 36 + vc] = pk;
            }
        }
        __syncthreads();   // staging visible
    }
    // epilogue: reduce partial l, then O/l for both q-tiles
#pragma unroll
    for (int qi = 0; qi < 4; ++qi)
#pragma unroll
        for (int r = 0; r < 4; ++r) {
            float s = lrow[qi][r];
#pragma unroll
            for (int off = 1; off < 16; off <<= 1) s += __shfl_xor(s, off);
            lrow[qi][r] = s;
        }
#pragma unroll
    for (int qi = 0; qi < 4; ++qi) {
        const int qlo = ((qi >> 1) ? qbase1 : qbase0) + (qi & 1) * 16;
#pragma unroll
        for (int dj = 0; dj < 4; ++dj)
#pragma unroll
            for (int r = 0; r < 4; ++r) {
                const size_t o = ((size_t)(b * 1024 + qlo + l4 * 4 + r)) * 1024
                               + h * 64 + dj * 16 + l15;
                Og[o] = f2bf(O[qi][dj][r] / lrow[qi][r]);
            }
    }
}

// ---------------- orchestration
extern "C" void kernel_launch(void* const* d_in, const int* in_sizes, int n_in,
                              void* d_out, int out_size, void* d_ws, size_t ws_size,
                              hipStream_t stream)
{
    (void)in_sizes; (void)n_in; (void)out_size; (void)ws_size;
    const int*   idx  = (const int*)  d_in[0];
    const float* tok  = (const float*)d_in[1];
    const float* pos  = (const float*)d_in[2];
    const float* Wq   = (const float*)d_in[3];
    const float* Wk   = (const float*)d_in[4];
    const float* Wv   = (const float*)d_in[5];
    const float* Wo   = (const float*)d_in[6];
    const float* bo   = (const float*)d_in[7];
    const float* ln1g = (const float*)d_in[8];
    const float* ln1b = (const float*)d_in[9];
    const float* ln2g = (const float*)d_in[10];
    const float* ln2b = (const float*)d_in[11];
    const float* W1   = (const float*)d_in[12];
    const float* b1   = (const float*)d_in[13];
    const float* W2   = (const float*)d_in[14];
    const float* b2   = (const float*)d_in[15];
    const float* lnfg = (const float*)d_in[16];
    const float* lnfb = (const float*)d_in[17];
    const float* Wh   = (const float*)d_in[18];
    const float* bh   = (const float*)d_in[19];

    char* p = (char*)d_ws;
    float* x  = (float*)p; p += (size_t)8192 * 1024 * 4;
    u16* h    = (u16*)p;   p += (size_t)8192 * 1024 * 2;
    u16* qkv  = (u16*)p;   p += (size_t)8192 * 3072 * 2;
    u16* ab   = (u16*)p;   p += (size_t)8192 * 1024 * 2;
    u16* fb   = (u16*)p;   p += (size_t)8192 * 4096 * 2;
    u16* wqT  = (u16*)p;   p += (size_t)1024 * 1024 * 2;   // wq/wk/wv contiguous -> [3072][1024]
    u16* wkT  = (u16*)p;   p += (size_t)1024 * 1024 * 2;
    u16* wvT  = (u16*)p;   p += (size_t)1024 * 1024 * 2;
    u16* woT  = (u16*)p;   p += (size_t)1024 * 1024 * 2;
    u16* w1T  = (u16*)p;   p += (size_t)1024 * 4096 * 2;
    u16* w2T  = (u16*)p;   p += (size_t)4096 * 1024 * 2;
    u16* whT  = (u16*)p;   p += (size_t)1024 * 256 * 2;
    (void)wkT; (void)wvT;

    const dim3 tb(32, 8);
    for (int l = 0; l < 6; ++l) {
        transpose_all_k<<<12288, tb, 0, stream>>>(
            Wq + (size_t)l * 1048576, Wk + (size_t)l * 1048576,
            Wv + (size_t)l * 1048576, Wo + (size_t)l * 1048576,
            W1 + (size_t)l * 4194304, W2 + (size_t)l * 4194304,
            wqT, woT, w1T, w2T);

        if (l == 0)
            embed_ln_k<<<8192, 256, 0, stream>>>(idx, tok, pos, ln1g, ln1b, x, h);
        else
            ln_k<<<8192, 256, 0, stream>>>(x, ln1g + l * 1024, ln1b + l * 1024, h);
        gemm_bt<0><<<1536, 256, 0, stream>>>(h, wqT, nullptr, nullptr, qkv, nullptr, 3072, 1024, 24);
        attn_mfma_k<<<dim3(4, 128), 256, 0, stream>>>(qkv, ab);
        gemm_n64<1><<<1024, 256, 0, stream>>>(ab, woT, bo + l * 1024, x, nullptr, 1024, 1024, 16);
        ln_k<<<8192, 256, 0, stream>>>(x, ln2g + l * 1024, ln2b + l * 1024, h);
        gemm_bt<2><<<2048, 256, 0, stream>>>(h, w1T, b1 + l * 4096, nullptr, fb, nullptr, 4096, 1024, 32);
        gemm_n64<1><<<1024, 256, 0, stream>>>(fb, w2T, b2 + l * 1024, x, nullptr, 1024, 4096, 16);
    }
    transpose_k<<<dim3(8, 32), tb, 0, stream>>>(Wh, whT, 1024, 256);
    ln_k<<<8192, 256, 0, stream>>>(x, lnfg, lnfb, h);
    gemm_n64<3><<<256, 256, 0, stream>>>(h, whT, bh, nullptr, (float*)d_out, 256, 1024, 4);
}